// Round 1
// baseline (173.320 us; speedup 1.0000x reference)
//
#include <hip/hip_runtime.h>
#include <cstddef>

#define TDIM 1024
#define SEQ 8192
#define NROWS 4096

typedef float f32x4 __attribute__((ext_vector_type(4)));

__global__ __launch_bounds__(256) void hist_kernel(const int* __restrict__ his,
                                                   int* __restrict__ counts) {
    __shared__ int lc[TDIM];
    const int tid = threadIdx.x;
    for (int t = tid; t < TDIM; t += 256) lc[t] = 0;
    __syncthreads();
    const int base = blockIdx.x * 1024;  // 8 blocks x 1024 entries = 8192
    for (int i = tid; i < 1024; i += 256) {
        int h = his[base + i];
        atomicAdd(&lc[h], 1);
    }
    __syncthreads();
    for (int t = tid; t < TDIM; t += 256) {
        int c = lc[t];
        if (c) atomicAdd(&counts[t], c);
    }
}

// Block r (0..1023): compute softmax prob table for table-value r, then
// gather the unique output row G[r][j] = prob[his[j]].
__global__ __launch_bounds__(256) void unique_row_kernel(
    const int* __restrict__ his, const float* __restrict__ M,
    const int* __restrict__ counts, float* __restrict__ G)
{
    __shared__ float prob[TDIM];
    __shared__ float red[16];
    const int tid = threadIdx.x;
    const int r = blockIdx.x;                // table value, not output row
    const float* Mrow = M + (size_t)r * TDIM;

    float m[4];
    int   c[4];
#pragma unroll
    for (int k = 0; k < 4; ++k) {
        int t = tid + 256 * k;
        m[k] = Mrow[t];
        c[k] = counts[t];
    }

    // masked block max over table columns actually present in his
    float lmax = -3.402823466e38f;
#pragma unroll
    for (int k = 0; k < 4; ++k)
        if (c[k] > 0) lmax = fmaxf(lmax, m[k]);
#pragma unroll
    for (int off = 32; off > 0; off >>= 1)
        lmax = fmaxf(lmax, __shfl_down(lmax, off, 64));
    const int wave = tid >> 6, lane = tid & 63;
    if (lane == 0) red[wave] = lmax;
    __syncthreads();
    if (tid == 0) {
        float g = red[0];
        for (int w = 1; w < 4; ++w) g = fmaxf(g, red[w]);
        red[8] = g;
    }
    __syncthreads();
    const float gmax = red[8];

    // histogram-weighted exp sum: sum = sum_t c[t] * exp(M[r][t] - max)
    float e[4];
    float lsum = 0.f;
#pragma unroll
    for (int k = 0; k < 4; ++k) {
        e[k] = __expf(m[k] - gmax);
        lsum += (float)c[k] * e[k];
    }
#pragma unroll
    for (int off = 32; off > 0; off >>= 1)
        lsum += __shfl_down(lsum, off, 64);
    if (lane == 0) red[4 + wave] = lsum;
    __syncthreads();
    if (tid == 0) {
        float s = red[4] + red[5] + red[6] + red[7];
        red[9] = 1.0f / s;
    }
    __syncthreads();
    const float inv = red[9];

#pragma unroll
    for (int k = 0; k < 4; ++k)
        prob[tid + 256 * k] = e[k] * inv;
    __syncthreads();

    // gather the unique row: G[r][j] = prob[his[j]]
    const int4* his4 = (const int4*)his;     // 2048 int4
    f32x4* g4 = (f32x4*)(G + (size_t)r * SEQ);
#pragma unroll
    for (int it = 0; it < 8; ++it) {
        int j4 = it * 256 + tid;
        int4 h = his4[j4];
        f32x4 o;
        o.x = prob[h.x];
        o.y = prob[h.y];
        o.z = prob[h.z];
        o.w = prob[h.w];
        g4[j4] = o;
    }
}

// out[row] = G[cur[row]] — pure streaming replication.
// Reads of G hit L2/LLC (32 MB table, each row reused ~4x);
// non-temporal stores keep the never-re-read output from thrashing L2.
__global__ __launch_bounds__(256) void replicate_kernel(
    const int* __restrict__ cur, const float* __restrict__ G,
    float* __restrict__ out)
{
    const int row = blockIdx.x;
    const int r = cur[row];                  // wave-uniform broadcast load
    const f32x4* __restrict__ src = (const f32x4*)(G + (size_t)r * SEQ);
    f32x4* __restrict__ dst = (f32x4*)(out + (size_t)row * SEQ);
#pragma unroll
    for (int it = 0; it < 8; ++it) {
        int j = it * 256 + threadIdx.x;
        f32x4 v = src[j];
        __builtin_nontemporal_store(v, &dst[j]);
    }
}

// Fallback (proven path from the previous session) if workspace is too small.
__global__ __launch_bounds__(256) void softmax_gather_kernel(
    const int* __restrict__ his, const int* __restrict__ cur,
    const float* __restrict__ M, const int* __restrict__ counts,
    float* __restrict__ out)
{
    __shared__ float prob[TDIM];
    __shared__ float red[16];
    const int tid = threadIdx.x;
    const int row = blockIdx.x;
    const int r = cur[row];
    const float* Mrow = M + (size_t)r * TDIM;

    float m[4];
    int   c[4];
#pragma unroll
    for (int k = 0; k < 4; ++k) {
        int t = tid + 256 * k;
        m[k] = Mrow[t];
        c[k] = counts[t];
    }

    float lmax = -3.402823466e38f;
#pragma unroll
    for (int k = 0; k < 4; ++k)
        if (c[k] > 0) lmax = fmaxf(lmax, m[k]);
#pragma unroll
    for (int off = 32; off > 0; off >>= 1)
        lmax = fmaxf(lmax, __shfl_down(lmax, off, 64));
    const int wave = tid >> 6, lane = tid & 63;
    if (lane == 0) red[wave] = lmax;
    __syncthreads();
    if (tid == 0) {
        float g = red[0];
        for (int w = 1; w < 4; ++w) g = fmaxf(g, red[w]);
        red[8] = g;
    }
    __syncthreads();
    const float gmax = red[8];

    float e[4];
    float lsum = 0.f;
#pragma unroll
    for (int k = 0; k < 4; ++k) {
        e[k] = __expf(m[k] - gmax);
        lsum += (float)c[k] * e[k];
    }
#pragma unroll
    for (int off = 32; off > 0; off >>= 1)
        lsum += __shfl_down(lsum, off, 64);
    if (lane == 0) red[4 + wave] = lsum;
    __syncthreads();
    if (tid == 0) {
        float s = red[4] + red[5] + red[6] + red[7];
        red[9] = 1.0f / s;
    }
    __syncthreads();
    const float inv = red[9];

#pragma unroll
    for (int k = 0; k < 4; ++k)
        prob[tid + 256 * k] = e[k] * inv;
    __syncthreads();

    const int4* his4 = (const int4*)his;
    float4* out4 = (float4*)(out + (size_t)row * SEQ);
#pragma unroll
    for (int it = 0; it < 8; ++it) {
        int j4 = it * 256 + tid;
        int4 h = his4[j4];
        float4 o;
        o.x = prob[h.x];
        o.y = prob[h.y];
        o.z = prob[h.z];
        o.w = prob[h.w];
        out4[j4] = o;
    }
}

extern "C" void kernel_launch(void* const* d_in, const int* in_sizes, int n_in,
                              void* d_out, int out_size, void* d_ws, size_t ws_size,
                              hipStream_t stream) {
    const int*   his = (const int*)d_in[0];    // (8192,) int32 in [0,1024)
    const int*   cur = (const int*)d_in[1];    // (4096,) int32 in [0,1024)
    const float* M   = (const float*)d_in[2];  // (1024,1024) fp32
    float* out = (float*)d_out;                // (4096,8192) fp32
    int* counts = (int*)d_ws;                  // 4 KB scratch at offset 0

    const size_t need = 4096 + (size_t)TDIM * SEQ * sizeof(float); // 4 KB + 32 MB

    hipMemsetAsync(counts, 0, TDIM * sizeof(int), stream);
    hist_kernel<<<8, 256, 0, stream>>>(his, counts);

    if (ws_size >= need) {
        float* G = (float*)((char*)d_ws + 4096);   // 32 MB unique-row table
        unique_row_kernel<<<TDIM, 256, 0, stream>>>(his, M, counts, G);
        replicate_kernel<<<NROWS, 256, 0, stream>>>(cur, G, out);
    } else {
        softmax_gather_kernel<<<NROWS, 256, 0, stream>>>(his, cur, M, counts, out);
    }
}

// Round 2
// 143.615 us; speedup vs baseline: 1.2068x; 1.2068x over previous
//
#include <hip/hip_runtime.h>
#include <cstddef>

#define TDIM 1024
#define SEQ 8192
#define NROWS 4096

typedef float f32x4 __attribute__((ext_vector_type(4)));

// One block per output row. Fully fused:
//   1. block-local histogram of his (LDS atomics, his cached in registers)
//   2. masked max + histogram-weighted exp-sum over the 1024 table columns
//   3. prob table in LDS (reusing the histogram buffer)
//   4. gather from registers + coalesced float4 write
__global__ __launch_bounds__(256) void fused_kernel(
    const int* __restrict__ his, const int* __restrict__ cur,
    const float* __restrict__ M, float* __restrict__ out)
{
    __shared__ int lc[TDIM];      // histogram, later reused as prob table
    __shared__ float red[8];      // [0..3] max partials, [4..7] sum partials
    float* prob = (float*)lc;

    const int tid = threadIdx.x;
    const int row = blockIdx.x;
    const int r = cur[row];                    // wave-uniform broadcast load
    const float* Mrow = M + (size_t)r * TDIM;

    // zero histogram
#pragma unroll
    for (int k = 0; k < 4; ++k) lc[tid + 256 * k] = 0;

    // his into registers: int4 x 8 = 32 indices/thread (reused for gather)
    const int4* his4 = (const int4*)his;       // 2048 int4
    int4 h[8];
#pragma unroll
    for (int it = 0; it < 8; ++it) h[it] = his4[it * 256 + tid];

    // M row (L2-resident after first touch; 4 MB table fits per-XCD L2)
    float m[4];
#pragma unroll
    for (int k = 0; k < 4; ++k) m[k] = Mrow[tid + 256 * k];

    __syncthreads();                           // histogram zeroed

    // block-local histogram
#pragma unroll
    for (int it = 0; it < 8; ++it) {
        atomicAdd(&lc[h[it].x], 1);
        atomicAdd(&lc[h[it].y], 1);
        atomicAdd(&lc[h[it].z], 1);
        atomicAdd(&lc[h[it].w], 1);
    }
    __syncthreads();

    int c[4];
#pragma unroll
    for (int k = 0; k < 4; ++k) c[k] = lc[tid + 256 * k];

    // --- masked block max over table columns actually present in his ---
    float lmax = -3.402823466e38f;
#pragma unroll
    for (int k = 0; k < 4; ++k)
        if (c[k] > 0) lmax = fmaxf(lmax, m[k]);
#pragma unroll
    for (int off = 32; off > 0; off >>= 1)
        lmax = fmaxf(lmax, __shfl_down(lmax, off, 64));
    const int wave = tid >> 6, lane = tid & 63;
    if (lane == 0) red[wave] = lmax;
    __syncthreads();
    const float gmax = fmaxf(fmaxf(red[0], red[1]), fmaxf(red[2], red[3]));

    // --- histogram-weighted exp sum: sum_t c[t] * exp(M[r][t] - max) ---
    float e[4];
    float lsum = 0.f;
#pragma unroll
    for (int k = 0; k < 4; ++k) {
        e[k] = __expf(m[k] - gmax);
        lsum += (float)c[k] * e[k];
    }
#pragma unroll
    for (int off = 32; off > 0; off >>= 1)
        lsum += __shfl_down(lsum, off, 64);
    if (lane == 0) red[4 + wave] = lsum;
    __syncthreads();
    const float inv = 1.0f / (red[4] + red[5] + red[6] + red[7]);

    // --- prob table into LDS (overwrites histogram; c[] already in regs) ---
#pragma unroll
    for (int k = 0; k < 4; ++k)
        prob[tid + 256 * k] = e[k] * inv;
    __syncthreads();

    // --- gather from registers + coalesced float4 write ---
    f32x4* out4 = (f32x4*)(out + (size_t)row * SEQ);
#pragma unroll
    for (int it = 0; it < 8; ++it) {
        f32x4 o;
        o.x = prob[h[it].x];
        o.y = prob[h[it].y];
        o.z = prob[h[it].z];
        o.w = prob[h[it].w];
        out4[it * 256 + tid] = o;
    }
}

extern "C" void kernel_launch(void* const* d_in, const int* in_sizes, int n_in,
                              void* d_out, int out_size, void* d_ws, size_t ws_size,
                              hipStream_t stream) {
    const int*   his = (const int*)d_in[0];    // (8192,) int32 in [0,1024)
    const int*   cur = (const int*)d_in[1];    // (4096,) int32 in [0,1024)
    const float* M   = (const float*)d_in[2];  // (1024,1024) fp32
    float* out = (float*)d_out;                // (4096,8192) fp32
    (void)d_ws; (void)ws_size;

    fused_kernel<<<NROWS, 256, 0, stream>>>(his, cur, M, out);
}